// Round 16
// baseline (166.084 us; speedup 1.0000x reference)
//
#include <hip/hip_runtime.h>

#define D_IN 256
#define D_HID 128
#define NPB 512          // nodes per bucket
#define BCAP 8192        // per-bucket capacity (mean ~6400, +22 sigma)

typedef __bf16 bf16;
typedef bf16 bf16x8 __attribute__((ext_vector_type(8)));
typedef float f32x4 __attribute__((ext_vector_type(4)));
typedef unsigned short u16;
typedef const __attribute__((address_space(1))) unsigned gu32;
typedef __attribute__((address_space(3))) unsigned lu32;

__device__ __forceinline__ float bfw(int e) {
  union { u16 u; bf16 b; } cv;
  cv.u = (u16)(((unsigned)e) >> 16);
  return (float)cv.b;
}

// ---------------- prep: zero padded bucket counters + pack W + fcwT ----------
__global__ void k_prep(const float* __restrict__ W1, const float* __restrict__ W2,
                       const float* __restrict__ W3, const float* __restrict__ fcw,
                       bf16* __restrict__ B1, bf16* __restrict__ B2,
                       bf16* __restrict__ B3, float* __restrict__ fcwT,
                       int* __restrict__ gcnt, int ncnt) {
  int idx = blockIdx.x * blockDim.x + threadIdx.x;
  {
    const float* W; bf16* B; int r;
    if (idx < 32768)      { W = W1; B = B1; r = idx; }
    else if (idx < 49152) { W = W2; B = B2; r = idx - 32768; }
    else                  { W = W3; B = B3; r = idx - 49152; }
    int e = r & 7, l = (r >> 3) & 63, f = r >> 9;
    int ct = f & 7, kt = f >> 3;
    int k = kt * 32 + ((l >> 4) << 3) + e;
    int c = ct * 16 + (l & 15);
    B[r] = (bf16)W[k * 128 + c];
  }
  if (idx < 2048) {
    int c = idx >> 7, k = idx & 127;
    fcwT[idx] = fcw[k * 16 + c];
  }
  if (idx < ncnt) gcnt[idx] = 0;
}

// ---------------- merged: CSR bin (blocks < BB)  ||  gemm1 x@W1 (rest) -------
__global__ __launch_bounds__(256) void k_bin_gemm1(
    const int* __restrict__ src, const int* __restrict__ dst,
    const float* __restrict__ ew, int E, int* __restrict__ gcnt,
    int2* __restrict__ bins, int BB,
    const float* __restrict__ x, const bf16* __restrict__ Bp,
    bf16* __restrict__ Hb, int N) {
  __shared__ __align__(16) char smraw[65536];
  const int t = threadIdx.x;

  if (blockIdx.x < BB) {
    int* lcnt  = (int*)smraw;
    int* lbase = lcnt + 128;
    int* lcur  = lcnt + 256;
    int* gbase = lcnt + 384;
    int* stotp = lcnt + 512;
    int2* stage = (int2*)(smraw + 4096);
    const int e0 = blockIdx.x * 2048;

    if (t < 128) lcnt[t] = 0;
    __syncthreads();

    int2 ent[8]; int bk[8];
    #pragma unroll
    for (int i = 0; i < 8; ++i) {
      int e = e0 + i * 256 + t;
      bool v = e < E;
      int d = v ? dst[e] : 0;
      int s = v ? src[e] : 0;
      float w = v ? ew[e] : 0.f;
      int b = d >> 9;
      bk[i] = v ? b : -1;
      ent[i] = make_int2(s | ((d & 511) << 16) | (b << 25), __float_as_int(w));
      if (v) atomicAdd(&lcnt[b], 1);
    }
    __syncthreads();

    int v = (t < 128) ? lcnt[t] : 0;
    if (t < 128) lbase[t] = v;
    __syncthreads();
    for (int off = 1; off < 128; off <<= 1) {
      int u = (t < 128 && t >= off) ? lbase[t - off] : 0;
      __syncthreads();
      if (t < 128) lbase[t] += u;
      __syncthreads();
    }
    if (t == 127) *stotp = lbase[127];
    if (t < 128) {
      int ex = lbase[t] - v;
      lbase[t] = ex;
      lcur[t] = ex;
      gbase[t] = (v > 0) ? atomicAdd(&gcnt[t * 16], v) : 0;
    }
    __syncthreads();

    #pragma unroll
    for (int i = 0; i < 8; ++i) {
      if (bk[i] >= 0) {
        int pos = atomicAdd(&lcur[bk[i]], 1);
        stage[pos] = ent[i];
      }
    }
    __syncthreads();

    const int tot = *stotp;
    for (int j = t; j < tot; j += 256) {
      int2 en = stage[j];
      int b = (en.x >> 25) & 0x7F;
      int gp = gbase[b] + (j - lbase[b]);
      if (gp < BCAP)
        bins[(size_t)b * BCAP + gp] = make_int2(en.x & 0x01FFFFFF, en.y);
    }
  } else {
    constexpr int K = 256, NKT = 8, NST = 16;
    bf16* Bs = (bf16*)smraw;            // 64 KB
    const int wave = t >> 6;
    const int lane = t & 63;
    const int l16 = lane & 15;
    const int g = lane >> 4;
    const int row0 = (blockIdx.x - BB) * 64 + wave * 16;
    const int arow = row0 + l16;
    const int arow_c = (arow < N) ? arow : (N - 1);

    #pragma unroll
    for (int i = 0; i < NST; ++i) {
      const bf16* gsrc = Bp + (size_t)(i * 256 + t) * 8;
      bf16* ldst = Bs + (size_t)(i * 256 + (t & ~63)) * 8;
      __builtin_amdgcn_global_load_lds((gu32*)gsrc, (lu32*)ldst, 16, 0, 0);
    }

    bf16x8 afr[NKT];
    {
      const float* Af = x + (size_t)arow_c * K + g * 8;
      f32x4 f0[NKT], f1[NKT];
      #pragma unroll
      for (int kt = 0; kt < NKT; ++kt) {
        f0[kt] = *reinterpret_cast<const f32x4*>(Af + kt * 32);
        f1[kt] = *reinterpret_cast<const f32x4*>(Af + kt * 32 + 4);
      }
      #pragma unroll
      for (int kt = 0; kt < NKT; ++kt) {
        bf16x8 a;
        a[0] = (bf16)f0[kt][0]; a[1] = (bf16)f0[kt][1];
        a[2] = (bf16)f0[kt][2]; a[3] = (bf16)f0[kt][3];
        a[4] = (bf16)f1[kt][0]; a[5] = (bf16)f1[kt][1];
        a[6] = (bf16)f1[kt][2]; a[7] = (bf16)f1[kt][3];
        afr[kt] = a;
      }
    }
    __syncthreads();

    f32x4 acc[8];
    #pragma unroll
    for (int ct = 0; ct < 8; ++ct) acc[ct] = f32x4{0.f, 0.f, 0.f, 0.f};
    #pragma unroll
    for (int kt = 0; kt < NKT; ++kt) {
      #pragma unroll
      for (int ct = 0; ct < 8; ++ct) {
        bf16x8 b = *reinterpret_cast<const bf16x8*>(Bs + (kt * 8 + ct) * 512 + lane * 8);
        acc[ct] = __builtin_amdgcn_mfma_f32_16x16x32_bf16(afr[kt], b, acc[ct], 0, 0, 0);
      }
    }

    const int orow = row0 + 4 * g;
    #pragma unroll
    for (int ct = 0; ct < 8; ++ct) {
      #pragma unroll
      for (int r = 0; r < 4; ++r) {
        if (orow + r < N)
          Hb[(size_t)(orow + r) * 128 + ct * 16 + l16] = (bf16)acc[ct][r];
      }
    }
  }
}

// ---------------- per-bucket build (self-computed prefix) -> rptr, esw -------
__global__ __launch_bounds__(512) void k_build(const int2* __restrict__ bins,
                                               const int* __restrict__ gcnt,
                                               int* __restrict__ rptr,
                                               int* __restrict__ esw, int N, int NBK) {
  __shared__ int deg[512], sm[512], cur[512];
  __shared__ int pre[128];
  const int b = blockIdx.x, t = threadIdx.x;
  const int n0 = b << 9;
  deg[t] = 0;
  int bv = (t < 128 && t < NBK) ? min(gcnt[t * 16], BCAP) : 0;
  if (t < 128) pre[t] = bv;
  __syncthreads();
  for (int off = 1; off < 128; off <<= 1) {
    int u = (t < 128 && t >= off) ? pre[t - off] : 0;
    __syncthreads();
    if (t < 128) pre[t] += u;
    __syncthreads();
  }
  const int cnt = min(gcnt[b * 16], BCAP);
  const int base = pre[b] - cnt;
  if (b == 0 && t == 0) rptr[N] = pre[NBK - 1];
  const int2* bp = bins + (size_t)b * BCAP;
  for (int i = t; i < cnt; i += 512) atomicAdd(&deg[(bp[i].x >> 16) & 511], 1);
  __syncthreads();
  sm[t] = deg[t];
  __syncthreads();
  for (int off = 1; off < 512; off <<= 1) {
    int u = (t >= off) ? sm[t - off] : 0;
    __syncthreads();
    sm[t] += u;
    __syncthreads();
  }
  int ex = sm[t] - deg[t];
  cur[t] = ex;
  if (n0 + t < N) rptr[n0 + t] = base + ex;
  __syncthreads();
  for (int i = t; i < cnt; i += 512) {
    int2 en = bp[i];
    int pos = atomicAdd(&cur[(en.x >> 16) & 511], 1);
    union { bf16 b; u16 u; } cv;
    cv.b = (bf16)__int_as_float(en.y);
    esw[base + pos] = (((int)cv.u) << 16) | (en.x & 0xFFFF);
  }
}

// ---------------- MFMA GEMM (layers 2/3): bf16 A, async B stage --------------
template<int K>
__global__ __launch_bounds__(256) void k_gemm5(const bf16* __restrict__ Ain,
                                               const bf16* __restrict__ Bp,
                                               bf16* __restrict__ Hb, int N) {
  constexpr int NKT = K / 32;
  constexpr int NST = (K * 128) / (256 * 8);
  __shared__ bf16 Bs[K * 128];
  const int t = threadIdx.x;
  const int wave = t >> 6;
  const int lane = t & 63;
  const int l16 = lane & 15;
  const int g = lane >> 4;
  const int row0 = blockIdx.x * 64 + wave * 16;
  const int arow = row0 + l16;
  const int arow_c = (arow < N) ? arow : (N - 1);

  #pragma unroll
  for (int i = 0; i < NST; ++i) {
    const bf16* gsrc = Bp + (size_t)(i * 256 + t) * 8;
    bf16* ldst = Bs + (size_t)(i * 256 + (t & ~63)) * 8;
    __builtin_amdgcn_global_load_lds((gu32*)gsrc, (lu32*)ldst, 16, 0, 0);
  }

  bf16x8 afr[NKT];
  const bf16* Ab = Ain + (size_t)arow_c * K + g * 8;
  #pragma unroll
  for (int kt = 0; kt < NKT; ++kt)
    afr[kt] = *reinterpret_cast<const bf16x8*>(Ab + kt * 32);

  __syncthreads();

  f32x4 acc[8];
  #pragma unroll
  for (int ct = 0; ct < 8; ++ct) acc[ct] = f32x4{0.f, 0.f, 0.f, 0.f};
  #pragma unroll
  for (int kt = 0; kt < NKT; ++kt) {
    #pragma unroll
    for (int ct = 0; ct < 8; ++ct) {
      bf16x8 b = *reinterpret_cast<const bf16x8*>(Bs + (kt * 8 + ct) * 512 + lane * 8);
      acc[ct] = __builtin_amdgcn_mfma_f32_16x16x32_bf16(afr[kt], b, acc[ct], 0, 0, 0);
    }
  }

  const int orow = row0 + 4 * g;
  #pragma unroll
  for (int ct = 0; ct < 8; ++ct) {
    #pragma unroll
    for (int r = 0; r < 4; ++r) {
      if (orow + r < N)
        Hb[(size_t)(orow + r) * 128 + ct * 16 + l16] = (bf16)acc[ct][r];
    }
  }
}

// ---------------- aggregation (layers 1/2): bf16 out + relu ------------------
__global__ __launch_bounds__(256) void k_agg(const bf16* __restrict__ H,
                                             const int* __restrict__ rptr,
                                             const int* __restrict__ esw,
                                             const float* __restrict__ bias,
                                             bf16* __restrict__ out, int N) {
  const int wv = threadIdx.x >> 6;
  const int lane = threadIdx.x & 63;
  const int node = blockIdx.x * 8 + wv * 2 + (lane >> 5);
  if (node >= N) return;
  const int l16 = lane & 15;
  const int slot = (lane >> 4) & 1;
  const int p1 = rptr[node + 1];
  float a[8];
  #pragma unroll
  for (int j = 0; j < 8; ++j) a[j] = 0.f;

  int p = rptr[node] + slot;
  for (; p + 2 < p1; p += 4) {
    int e0 = esw[p];
    int e1 = esw[p + 2];
    bf16x8 h0 = *reinterpret_cast<const bf16x8*>(H + (size_t)(e0 & 0xFFFF) * 128 + l16 * 8);
    bf16x8 h1 = *reinterpret_cast<const bf16x8*>(H + (size_t)(e1 & 0xFFFF) * 128 + l16 * 8);
    float w0 = bfw(e0), w1 = bfw(e1);
    #pragma unroll
    for (int j = 0; j < 8; ++j)
      a[j] += w0 * (float)h0[j] + w1 * (float)h1[j];
  }
  if (p < p1) {
    int e0 = esw[p];
    bf16x8 h0 = *reinterpret_cast<const bf16x8*>(H + (size_t)(e0 & 0xFFFF) * 128 + l16 * 8);
    float w0 = bfw(e0);
    #pragma unroll
    for (int j = 0; j < 8; ++j)
      a[j] += w0 * (float)h0[j];
  }
  #pragma unroll
  for (int j = 0; j < 8; ++j) a[j] += __shfl_xor(a[j], 16);

  if ((lane & 16) == 0) {
    float4 b0 = *reinterpret_cast<const float4*>(bias + l16 * 8);
    float4 b1 = *reinterpret_cast<const float4*>(bias + l16 * 8 + 4);
    bf16x8 o;
    o[0] = (bf16)fmaxf(a[0] + b0.x, 0.f); o[1] = (bf16)fmaxf(a[1] + b0.y, 0.f);
    o[2] = (bf16)fmaxf(a[2] + b0.z, 0.f); o[3] = (bf16)fmaxf(a[3] + b0.w, 0.f);
    o[4] = (bf16)fmaxf(a[4] + b1.x, 0.f); o[5] = (bf16)fmaxf(a[5] + b1.y, 0.f);
    o[6] = (bf16)fmaxf(a[6] + b1.z, 0.f); o[7] = (bf16)fmaxf(a[7] + b1.w, 0.f);
    *reinterpret_cast<bf16x8*>(out + (size_t)node * 128 + l16 * 8) = o;
  }
}

// ---------------- aggregation (final layer): emb = agg(G) + b (f32) ----------
__global__ __launch_bounds__(256) void k_agg_f32(const bf16* __restrict__ H,
                                                 const int* __restrict__ rptr,
                                                 const int* __restrict__ esw,
                                                 const float* __restrict__ bias,
                                                 float* __restrict__ out, int N) {
  const int wv = threadIdx.x >> 6;
  const int lane = threadIdx.x & 63;
  const int node = blockIdx.x * 8 + wv * 2 + (lane >> 5);
  if (node >= N) return;
  const int l16 = lane & 15;
  const int slot = (lane >> 4) & 1;
  const int p1 = rptr[node + 1];
  float a[8];
  #pragma unroll
  for (int j = 0; j < 8; ++j) a[j] = 0.f;

  int p = rptr[node] + slot;
  for (; p + 2 < p1; p += 4) {
    int e0 = esw[p];
    int e1 = esw[p + 2];
    bf16x8 h0 = *reinterpret_cast<const bf16x8*>(H + (size_t)(e0 & 0xFFFF) * 128 + l16 * 8);
    bf16x8 h1 = *reinterpret_cast<const bf16x8*>(H + (size_t)(e1 & 0xFFFF) * 128 + l16 * 8);
    float w0 = bfw(e0), w1 = bfw(e1);
    #pragma unroll
    for (int j = 0; j < 8; ++j)
      a[j] += w0 * (float)h0[j] + w1 * (float)h1[j];
  }
  if (p < p1) {
    int e0 = esw[p];
    bf16x8 h0 = *reinterpret_cast<const bf16x8*>(H + (size_t)(e0 & 0xFFFF) * 128 + l16 * 8);
    float w0 = bfw(e0);
    #pragma unroll
    for (int j = 0; j < 8; ++j)
      a[j] += w0 * (float)h0[j];
  }
  #pragma unroll
  for (int j = 0; j < 8; ++j) a[j] += __shfl_xor(a[j], 16);

  if ((lane & 16) == 0) {
    float4 b0 = *reinterpret_cast<const float4*>(bias + l16 * 8);
    float4 b1 = *reinterpret_cast<const float4*>(bias + l16 * 8 + 4);
    f32x4 o0 = {a[0] + b0.x, a[1] + b0.y, a[2] + b0.z, a[3] + b0.w};
    f32x4 o1 = {a[4] + b1.x, a[5] + b1.y, a[6] + b1.z, a[7] + b1.w};
    float* op = out + (size_t)node * 128 + l16 * 8;
    *reinterpret_cast<f32x4*>(op) = o0;
    *reinterpret_cast<f32x4*>(op + 4) = o1;
  }
}

// ---------------- fc + log_softmax: one node per thread, fcw staged in LDS ----
__global__ __launch_bounds__(256) void k_fc_lsm(const float* __restrict__ emb,
                                                const float* __restrict__ fcwT,
                                                const float* __restrict__ fcb,
                                                float* __restrict__ out, int N) {
  __shared__ float wl[16 * 128];
  __shared__ float fb[16];
  const int t = threadIdx.x;
  {
    const float4* s4 = reinterpret_cast<const float4*>(fcwT);
    float4* d4 = reinterpret_cast<float4*>(wl);
    d4[t] = s4[t];
    d4[t + 256] = s4[t + 256];
  }
  if (t < 16) fb[t] = fcb[t];
  __syncthreads();

  const int node = blockIdx.x * 256 + t;
  if (node >= N) return;
  const float4* er = reinterpret_cast<const float4*>(emb + (size_t)node * 128);

  float acc[16];
  #pragma unroll
  for (int c = 0; c < 16; ++c) acc[c] = fb[c];

  #pragma unroll 4
  for (int k4 = 0; k4 < 32; ++k4) {
    float4 e = er[k4];
    #pragma unroll
    for (int c = 0; c < 16; ++c) {
      float4 w = reinterpret_cast<const float4*>(wl + c * 128)[k4];
      acc[c] += e.x * w.x + e.y * w.y + e.z * w.z + e.w * w.w;
    }
  }

  float m = acc[0];
  #pragma unroll
  for (int c = 1; c < 16; ++c) m = fmaxf(m, acc[c]);
  float s = 0.f;
  #pragma unroll
  for (int c = 0; c < 16; ++c) s += __expf(acc[c] - m);
  float lse = m + __logf(s);
  float* op = out + (size_t)node * 16;
  #pragma unroll
  for (int c4 = 0; c4 < 4; ++c4) {
    f32x4 o = {acc[c4 * 4] - lse, acc[c4 * 4 + 1] - lse,
               acc[c4 * 4 + 2] - lse, acc[c4 * 4 + 3] - lse};
    *reinterpret_cast<f32x4*>(op + c4 * 4) = o;
  }
}

extern "C" void kernel_launch(void* const* d_in, const int* in_sizes, int n_in,
                              void* d_out, int out_size, void* d_ws, size_t ws_size,
                              hipStream_t stream) {
  const float* x   = (const float*)d_in[0];
  const float* ew  = (const float*)d_in[1];
  const float* W1  = (const float*)d_in[2];
  const float* b1  = (const float*)d_in[3];
  const float* W2  = (const float*)d_in[4];
  const float* b2  = (const float*)d_in[5];
  const float* W3  = (const float*)d_in[6];
  const float* b3  = (const float*)d_in[7];
  const float* fcw = (const float*)d_in[8];
  const float* fcb = (const float*)d_in[9];
  const int*   ei  = (const int*)d_in[10];

  const int N = in_sizes[0] / D_IN;     // 50000
  const int E = in_sizes[1];            // 625000
  const int* srcI = ei;
  const int* dstI = ei + E;
  const int NBK = (N + NPB - 1) / NPB;  // 98
  const int ncnt = NBK * 16;

  char* ws = (char*)d_ws;
  size_t o = 0;
  auto take = [&](size_t b) -> char* {
    char* p = ws + o;
    o += (b + 255) & ~(size_t)255;
    return p;
  };
  bf16*  hb0  = (bf16*)take((size_t)N * 128 * 2);
  bf16*  hb1  = (bf16*)take((size_t)N * 128 * 2);
  bf16*  Bp1  = (bf16*)take((size_t)D_IN * 128 * 2);
  bf16*  Bp2  = (bf16*)take((size_t)D_HID * 128 * 2);
  bf16*  Bp3  = (bf16*)take((size_t)D_HID * 128 * 2);
  float* fcwT = (float*)take((size_t)2048 * 4);
  int*   rptr = (int*)take((size_t)(N + 1) * 4);
  int*   gcnt = (int*)take((size_t)ncnt * 4);
  int2*  bins = (int2*)take((size_t)NBK * BCAP * 8);
  int*   esw  = (int*)take((size_t)E * 4);
  (void)ws_size; (void)n_in; (void)out_size;

  k_prep<<<256, 256, 0, stream>>>(W1, W2, W3, fcw, Bp1, Bp2, Bp3, fcwT, gcnt, ncnt);

  int bb = (E + 2047) / 2048;           // 306 bin blocks
  int gb = (N + 63) / 64;               // 782 gemm blocks
  k_bin_gemm1<<<bb + gb, 256, 0, stream>>>(srcI, dstI, ew, E, gcnt, bins, bb,
                                           x, Bp1, hb0, N);
  k_build<<<NBK, 512, 0, stream>>>(bins, gcnt, rptr, esw, N, NBK);

  float* emb = (float*)d_out;
  float* lsm = emb + (size_t)N * 128;
  int ab = (N + 7) / 8;

  k_agg<<<ab, 256, 0, stream>>>(hb0, rptr, esw, b1, hb1, N);
  k_gemm5<D_HID><<<gb, 256, 0, stream>>>(hb1, Bp2, hb0, N);
  k_agg<<<ab, 256, 0, stream>>>(hb0, rptr, esw, b2, hb1, N);
  k_gemm5<D_HID><<<gb, 256, 0, stream>>>(hb1, Bp3, hb0, N);
  k_agg_f32<<<ab, 256, 0, stream>>>(hb0, rptr, esw, b3, emb, N);
  k_fc_lsm<<<(N + 255) / 256, 256, 0, stream>>>(emb, fcwT, fcb, lsm, N);
}

// Round 17
// 162.896 us; speedup vs baseline: 1.0196x; 1.0196x over previous
//
#include <hip/hip_runtime.h>

#define D_IN 256
#define D_HID 128
#define NPB 512          // nodes per bucket
#define BCAP 8192        // per-bucket capacity (mean ~6400, +22 sigma)

typedef __bf16 bf16;
typedef bf16 bf16x8 __attribute__((ext_vector_type(8)));
typedef float f32x4 __attribute__((ext_vector_type(4)));
typedef unsigned short u16;
typedef const __attribute__((address_space(1))) unsigned gu32;
typedef __attribute__((address_space(3))) unsigned lu32;

__device__ __forceinline__ float bfw(int e) {
  union { u16 u; bf16 b; } cv;
  cv.u = (u16)(((unsigned)e) >> 16);
  return (float)cv.b;
}

// ---------------- prep: zero padded bucket counters + pack W + fcwT ----------
__global__ void k_prep(const float* __restrict__ W1, const float* __restrict__ W2,
                       const float* __restrict__ W3, const float* __restrict__ fcw,
                       bf16* __restrict__ B1, bf16* __restrict__ B2,
                       bf16* __restrict__ B3, float* __restrict__ fcwT,
                       int* __restrict__ gcnt, int ncnt) {
  int idx = blockIdx.x * blockDim.x + threadIdx.x;
  {
    const float* W; bf16* B; int r;
    if (idx < 32768)      { W = W1; B = B1; r = idx; }
    else if (idx < 49152) { W = W2; B = B2; r = idx - 32768; }
    else                  { W = W3; B = B3; r = idx - 49152; }
    int e = r & 7, l = (r >> 3) & 63, f = r >> 9;
    int ct = f & 7, kt = f >> 3;
    int k = kt * 32 + ((l >> 4) << 3) + e;
    int c = ct * 16 + (l & 15);
    B[r] = (bf16)W[k * 128 + c];
  }
  if (idx < 2048) {
    int c = idx >> 7, k = idx & 127;
    fcwT[idx] = fcw[k * 16 + c];
  }
  if (idx < ncnt) gcnt[idx] = 0;
}

// ---------------- merged: CSR bin (blocks < BB)  ||  gemm1 x@W1 (rest) -------
// 32 KB LDS (gemm1 stages W1 in 2 chunks) -> 5 blocks/CU for both branches.
__global__ __launch_bounds__(256) void k_bin_gemm1(
    const int* __restrict__ src, const int* __restrict__ dst,
    const float* __restrict__ ew, int E, int* __restrict__ gcnt,
    int2* __restrict__ bins, int BB,
    const float* __restrict__ x, const bf16* __restrict__ Bp,
    bf16* __restrict__ Hb, int N) {
  __shared__ __align__(16) char smraw[32768];
  const int t = threadIdx.x;

  if (blockIdx.x < BB) {
    int* lcnt  = (int*)smraw;
    int* lbase = lcnt + 128;
    int* lcur  = lcnt + 256;
    int* gbase = lcnt + 384;
    int* stotp = lcnt + 512;
    int2* stage = (int2*)(smraw + 4096);
    const int e0 = blockIdx.x * 2048;

    if (t < 128) lcnt[t] = 0;
    __syncthreads();

    int2 ent[8]; int bk[8];
    #pragma unroll
    for (int i = 0; i < 8; ++i) {
      int e = e0 + i * 256 + t;
      bool v = e < E;
      int d = v ? dst[e] : 0;
      int s = v ? src[e] : 0;
      float w = v ? ew[e] : 0.f;
      int b = d >> 9;
      bk[i] = v ? b : -1;
      ent[i] = make_int2(s | ((d & 511) << 16) | (b << 25), __float_as_int(w));
      if (v) atomicAdd(&lcnt[b], 1);
    }
    __syncthreads();

    int v = (t < 128) ? lcnt[t] : 0;
    if (t < 128) lbase[t] = v;
    __syncthreads();
    for (int off = 1; off < 128; off <<= 1) {
      int u = (t < 128 && t >= off) ? lbase[t - off] : 0;
      __syncthreads();
      if (t < 128) lbase[t] += u;
      __syncthreads();
    }
    if (t == 127) *stotp = lbase[127];
    if (t < 128) {
      int ex = lbase[t] - v;
      lbase[t] = ex;
      lcur[t] = ex;
      gbase[t] = (v > 0) ? atomicAdd(&gcnt[t * 16], v) : 0;
    }
    __syncthreads();

    #pragma unroll
    for (int i = 0; i < 8; ++i) {
      if (bk[i] >= 0) {
        int pos = atomicAdd(&lcur[bk[i]], 1);
        stage[pos] = ent[i];
      }
    }
    __syncthreads();

    const int tot = *stotp;
    for (int j = t; j < tot; j += 256) {
      int2 en = stage[j];
      int b = (en.x >> 25) & 0x7F;
      int gp = gbase[b] + (j - lbase[b]);
      if (gp < BCAP)
        bins[(size_t)b * BCAP + gp] = make_int2(en.x & 0x01FFFFFF, en.y);
    }
  } else {
    constexpr int K = 256;
    bf16* Bs = (bf16*)smraw;            // 32 KB (one chunk = kt 0..3)
    const int wave = t >> 6;
    const int lane = t & 63;
    const int l16 = lane & 15;
    const int g = lane >> 4;
    const int row0 = (blockIdx.x - BB) * 64 + wave * 16;
    const int arow = row0 + l16;
    const int arow_c = (arow < N) ? arow : (N - 1);

    // stage chunk 0 (frags 0..31 = kt 0..3): 8 x 16B/thread
    #pragma unroll
    for (int i = 0; i < 8; ++i) {
      const bf16* gsrc = Bp + (size_t)(i * 256 + t) * 8;
      bf16* ldst = Bs + (size_t)(i * 256 + (t & ~63)) * 8;
      __builtin_amdgcn_global_load_lds((gu32*)gsrc, (lu32*)ldst, 16, 0, 0);
    }

    // hoist ALL A loads (8 kt; overlap stage + maximize MLP)
    bf16x8 afr[8];
    {
      const float* Af = x + (size_t)arow_c * K + g * 8;
      f32x4 f0[8], f1[8];
      #pragma unroll
      for (int kt = 0; kt < 8; ++kt) {
        f0[kt] = *reinterpret_cast<const f32x4*>(Af + kt * 32);
        f1[kt] = *reinterpret_cast<const f32x4*>(Af + kt * 32 + 4);
      }
      #pragma unroll
      for (int kt = 0; kt < 8; ++kt) {
        bf16x8 a;
        a[0] = (bf16)f0[kt][0]; a[1] = (bf16)f0[kt][1];
        a[2] = (bf16)f0[kt][2]; a[3] = (bf16)f0[kt][3];
        a[4] = (bf16)f1[kt][0]; a[5] = (bf16)f1[kt][1];
        a[6] = (bf16)f1[kt][2]; a[7] = (bf16)f1[kt][3];
        afr[kt] = a;
      }
    }
    __syncthreads();                    // chunk0 + A complete

    f32x4 acc[8];
    #pragma unroll
    for (int ct = 0; ct < 8; ++ct) acc[ct] = f32x4{0.f, 0.f, 0.f, 0.f};
    #pragma unroll
    for (int kt = 0; kt < 4; ++kt) {
      #pragma unroll
      for (int ct = 0; ct < 8; ++ct) {
        bf16x8 b = *reinterpret_cast<const bf16x8*>(Bs + (kt * 8 + ct) * 512 + lane * 8);
        acc[ct] = __builtin_amdgcn_mfma_f32_16x16x32_bf16(afr[kt], b, acc[ct], 0, 0, 0);
      }
    }
    __syncthreads();                    // all waves done reading chunk0

    // stage chunk 1 (frags 32..63 = kt 4..7)
    #pragma unroll
    for (int i = 0; i < 8; ++i) {
      const bf16* gsrc = Bp + (size_t)((i + 8) * 256 + t) * 8;
      bf16* ldst = Bs + (size_t)(i * 256 + (t & ~63)) * 8;
      __builtin_amdgcn_global_load_lds((gu32*)gsrc, (lu32*)ldst, 16, 0, 0);
    }
    __syncthreads();                    // chunk1 complete

    #pragma unroll
    for (int kt = 4; kt < 8; ++kt) {
      #pragma unroll
      for (int ct = 0; ct < 8; ++ct) {
        bf16x8 b = *reinterpret_cast<const bf16x8*>(Bs + ((kt - 4) * 8 + ct) * 512 + lane * 8);
        acc[ct] = __builtin_amdgcn_mfma_f32_16x16x32_bf16(afr[kt], b, acc[ct], 0, 0, 0);
      }
    }

    const int orow = row0 + 4 * g;
    #pragma unroll
    for (int ct = 0; ct < 8; ++ct) {
      #pragma unroll
      for (int r = 0; r < 4; ++r) {
        if (orow + r < N)
          Hb[(size_t)(orow + r) * 128 + ct * 16 + l16] = (bf16)acc[ct][r];
      }
    }
  }
}

// ---------------- per-bucket build (self-computed prefix) -> rptr, esw -------
__global__ __launch_bounds__(512) void k_build(const int2* __restrict__ bins,
                                               const int* __restrict__ gcnt,
                                               int* __restrict__ rptr,
                                               int* __restrict__ esw, int N, int NBK) {
  __shared__ int deg[512], sm[512], cur[512];
  __shared__ int pre[128];
  const int b = blockIdx.x, t = threadIdx.x;
  const int n0 = b << 9;
  deg[t] = 0;
  int bv = (t < 128 && t < NBK) ? min(gcnt[t * 16], BCAP) : 0;
  if (t < 128) pre[t] = bv;
  __syncthreads();
  for (int off = 1; off < 128; off <<= 1) {
    int u = (t < 128 && t >= off) ? pre[t - off] : 0;
    __syncthreads();
    if (t < 128) pre[t] += u;
    __syncthreads();
  }
  const int cnt = min(gcnt[b * 16], BCAP);
  const int base = pre[b] - cnt;
  if (b == 0 && t == 0) rptr[N] = pre[NBK - 1];
  const int2* bp = bins + (size_t)b * BCAP;
  for (int i = t; i < cnt; i += 512) atomicAdd(&deg[(bp[i].x >> 16) & 511], 1);
  __syncthreads();
  sm[t] = deg[t];
  __syncthreads();
  for (int off = 1; off < 512; off <<= 1) {
    int u = (t >= off) ? sm[t - off] : 0;
    __syncthreads();
    sm[t] += u;
    __syncthreads();
  }
  int ex = sm[t] - deg[t];
  cur[t] = ex;
  if (n0 + t < N) rptr[n0 + t] = base + ex;
  __syncthreads();
  for (int i = t; i < cnt; i += 512) {
    int2 en = bp[i];
    int pos = atomicAdd(&cur[(en.x >> 16) & 511], 1);
    union { bf16 b; u16 u; } cv;
    cv.b = (bf16)__int_as_float(en.y);
    esw[base + pos] = (((int)cv.u) << 16) | (en.x & 0xFFFF);
  }
}

// ---------------- MFMA GEMM (layers 2/3): bf16 A, async B stage --------------
template<int K>
__global__ __launch_bounds__(256) void k_gemm5(const bf16* __restrict__ Ain,
                                               const bf16* __restrict__ Bp,
                                               bf16* __restrict__ Hb, int N) {
  constexpr int NKT = K / 32;
  constexpr int NST = (K * 128) / (256 * 8);
  __shared__ bf16 Bs[K * 128];
  const int t = threadIdx.x;
  const int wave = t >> 6;
  const int lane = t & 63;
  const int l16 = lane & 15;
  const int g = lane >> 4;
  const int row0 = blockIdx.x * 64 + wave * 16;
  const int arow = row0 + l16;
  const int arow_c = (arow < N) ? arow : (N - 1);

  #pragma unroll
  for (int i = 0; i < NST; ++i) {
    const bf16* gsrc = Bp + (size_t)(i * 256 + t) * 8;
    bf16* ldst = Bs + (size_t)(i * 256 + (t & ~63)) * 8;
    __builtin_amdgcn_global_load_lds((gu32*)gsrc, (lu32*)ldst, 16, 0, 0);
  }

  bf16x8 afr[NKT];
  const bf16* Ab = Ain + (size_t)arow_c * K + g * 8;
  #pragma unroll
  for (int kt = 0; kt < NKT; ++kt)
    afr[kt] = *reinterpret_cast<const bf16x8*>(Ab + kt * 32);

  __syncthreads();

  f32x4 acc[8];
  #pragma unroll
  for (int ct = 0; ct < 8; ++ct) acc[ct] = f32x4{0.f, 0.f, 0.f, 0.f};
  #pragma unroll
  for (int kt = 0; kt < NKT; ++kt) {
    #pragma unroll
    for (int ct = 0; ct < 8; ++ct) {
      bf16x8 b = *reinterpret_cast<const bf16x8*>(Bs + (kt * 8 + ct) * 512 + lane * 8);
      acc[ct] = __builtin_amdgcn_mfma_f32_16x16x32_bf16(afr[kt], b, acc[ct], 0, 0, 0);
    }
  }

  const int orow = row0 + 4 * g;
  #pragma unroll
  for (int ct = 0; ct < 8; ++ct) {
    #pragma unroll
    for (int r = 0; r < 4; ++r) {
      if (orow + r < N)
        Hb[(size_t)(orow + r) * 128 + ct * 16 + l16] = (bf16)acc[ct][r];
    }
  }
}

// ---------------- aggregation (layers 1/2): bf16 out + relu ------------------
__global__ __launch_bounds__(256) void k_agg(const bf16* __restrict__ H,
                                             const int* __restrict__ rptr,
                                             const int* __restrict__ esw,
                                             const float* __restrict__ bias,
                                             bf16* __restrict__ out, int N) {
  const int wv = threadIdx.x >> 6;
  const int lane = threadIdx.x & 63;
  const int node = blockIdx.x * 8 + wv * 2 + (lane >> 5);
  if (node >= N) return;
  const int l16 = lane & 15;
  const int slot = (lane >> 4) & 1;
  const int p1 = rptr[node + 1];
  float a[8];
  #pragma unroll
  for (int j = 0; j < 8; ++j) a[j] = 0.f;

  int p = rptr[node] + slot;
  for (; p + 2 < p1; p += 4) {
    int e0 = esw[p];
    int e1 = esw[p + 2];
    bf16x8 h0 = *reinterpret_cast<const bf16x8*>(H + (size_t)(e0 & 0xFFFF) * 128 + l16 * 8);
    bf16x8 h1 = *reinterpret_cast<const bf16x8*>(H + (size_t)(e1 & 0xFFFF) * 128 + l16 * 8);
    float w0 = bfw(e0), w1 = bfw(e1);
    #pragma unroll
    for (int j = 0; j < 8; ++j)
      a[j] += w0 * (float)h0[j] + w1 * (float)h1[j];
  }
  if (p < p1) {
    int e0 = esw[p];
    bf16x8 h0 = *reinterpret_cast<const bf16x8*>(H + (size_t)(e0 & 0xFFFF) * 128 + l16 * 8);
    float w0 = bfw(e0);
    #pragma unroll
    for (int j = 0; j < 8; ++j)
      a[j] += w0 * (float)h0[j];
  }
  #pragma unroll
  for (int j = 0; j < 8; ++j) a[j] += __shfl_xor(a[j], 16);

  if ((lane & 16) == 0) {
    float4 b0 = *reinterpret_cast<const float4*>(bias + l16 * 8);
    float4 b1 = *reinterpret_cast<const float4*>(bias + l16 * 8 + 4);
    bf16x8 o;
    o[0] = (bf16)fmaxf(a[0] + b0.x, 0.f); o[1] = (bf16)fmaxf(a[1] + b0.y, 0.f);
    o[2] = (bf16)fmaxf(a[2] + b0.z, 0.f); o[3] = (bf16)fmaxf(a[3] + b0.w, 0.f);
    o[4] = (bf16)fmaxf(a[4] + b1.x, 0.f); o[5] = (bf16)fmaxf(a[5] + b1.y, 0.f);
    o[6] = (bf16)fmaxf(a[6] + b1.z, 0.f); o[7] = (bf16)fmaxf(a[7] + b1.w, 0.f);
    *reinterpret_cast<bf16x8*>(out + (size_t)node * 128 + l16 * 8) = o;
  }
}

// ---------------- aggregation (final layer): emb = agg(G) + b (f32) ----------
__global__ __launch_bounds__(256) void k_agg_f32(const bf16* __restrict__ H,
                                                 const int* __restrict__ rptr,
                                                 const int* __restrict__ esw,
                                                 const float* __restrict__ bias,
                                                 float* __restrict__ out, int N) {
  const int wv = threadIdx.x >> 6;
  const int lane = threadIdx.x & 63;
  const int node = blockIdx.x * 8 + wv * 2 + (lane >> 5);
  if (node >= N) return;
  const int l16 = lane & 15;
  const int slot = (lane >> 4) & 1;
  const int p1 = rptr[node + 1];
  float a[8];
  #pragma unroll
  for (int j = 0; j < 8; ++j) a[j] = 0.f;

  int p = rptr[node] + slot;
  for (; p + 2 < p1; p += 4) {
    int e0 = esw[p];
    int e1 = esw[p + 2];
    bf16x8 h0 = *reinterpret_cast<const bf16x8*>(H + (size_t)(e0 & 0xFFFF) * 128 + l16 * 8);
    bf16x8 h1 = *reinterpret_cast<const bf16x8*>(H + (size_t)(e1 & 0xFFFF) * 128 + l16 * 8);
    float w0 = bfw(e0), w1 = bfw(e1);
    #pragma unroll
    for (int j = 0; j < 8; ++j)
      a[j] += w0 * (float)h0[j] + w1 * (float)h1[j];
  }
  if (p < p1) {
    int e0 = esw[p];
    bf16x8 h0 = *reinterpret_cast<const bf16x8*>(H + (size_t)(e0 & 0xFFFF) * 128 + l16 * 8);
    float w0 = bfw(e0);
    #pragma unroll
    for (int j = 0; j < 8; ++j)
      a[j] += w0 * (float)h0[j];
  }
  #pragma unroll
  for (int j = 0; j < 8; ++j) a[j] += __shfl_xor(a[j], 16);

  if ((lane & 16) == 0) {
    float4 b0 = *reinterpret_cast<const float4*>(bias + l16 * 8);
    float4 b1 = *reinterpret_cast<const float4*>(bias + l16 * 8 + 4);
    f32x4 o0 = {a[0] + b0.x, a[1] + b0.y, a[2] + b0.z, a[3] + b0.w};
    f32x4 o1 = {a[4] + b1.x, a[5] + b1.y, a[6] + b1.z, a[7] + b1.w};
    float* op = out + (size_t)node * 128 + l16 * 8;
    *reinterpret_cast<f32x4*>(op) = o0;
    *reinterpret_cast<f32x4*>(op + 4) = o1;
  }
}

// ---------------- fc + log_softmax: one node per thread, fcw staged in LDS ----
__global__ __launch_bounds__(256) void k_fc_lsm(const float* __restrict__ emb,
                                                const float* __restrict__ fcwT,
                                                const float* __restrict__ fcb,
                                                float* __restrict__ out, int N) {
  __shared__ float wl[16 * 128];
  __shared__ float fb[16];
  const int t = threadIdx.x;
  {
    const float4* s4 = reinterpret_cast<const float4*>(fcwT);
    float4* d4 = reinterpret_cast<float4*>(wl);
    d4[t] = s4[t];
    d4[t + 256] = s4[t + 256];
  }
  if (t < 16) fb[t] = fcb[t];
  __syncthreads();

  const int node = blockIdx.x * 256 + t;
  if (node >= N) return;
  const float4* er = reinterpret_cast<const float4*>(emb + (size_t)node * 128);

  float acc[16];
  #pragma unroll
  for (int c = 0; c < 16; ++c) acc[c] = fb[c];

  #pragma unroll 4
  for (int k4 = 0; k4 < 32; ++k4) {
    float4 e = er[k4];
    #pragma unroll
    for (int c = 0; c < 16; ++c) {
      float4 w = reinterpret_cast<const float4*>(wl + c * 128)[k4];
      acc[c] += e.x * w.x + e.y * w.y + e.z * w.z + e.w * w.w;
    }
  }

  float m = acc[0];
  #pragma unroll
  for (int c = 1; c < 16; ++c) m = fmaxf(m, acc[c]);
  float s = 0.f;
  #pragma unroll
  for (int c = 0; c < 16; ++c) s += __expf(acc[c] - m);
  float lse = m + __logf(s);
  float* op = out + (size_t)node * 16;
  #pragma unroll
  for (int c4 = 0; c4 < 4; ++c4) {
    f32x4 o = {acc[c4 * 4] - lse, acc[c4 * 4 + 1] - lse,
               acc[c4 * 4 + 2] - lse, acc[c4 * 4 + 3] - lse};
    *reinterpret_cast<f32x4*>(op + c4 * 4) = o;
  }
}

extern "C" void kernel_launch(void* const* d_in, const int* in_sizes, int n_in,
                              void* d_out, int out_size, void* d_ws, size_t ws_size,
                              hipStream_t stream) {
  const float* x   = (const float*)d_in[0];
  const float* ew  = (const float*)d_in[1];
  const float* W1  = (const float*)d_in[2];
  const float* b1  = (const float*)d_in[3];
  const float* W2  = (const float*)d_in[4];
  const float* b2  = (const float*)d_in[5];
  const float* W3  = (const float*)d_in[6];
  const float* b3  = (const float*)d_in[7];
  const float* fcw = (const float*)d_in[8];
  const float* fcb = (const float*)d_in[9];
  const int*   ei  = (const int*)d_in[10];

  const int N = in_sizes[0] / D_IN;     // 50000
  const int E = in_sizes[1];            // 625000
  const int* srcI = ei;
  const int* dstI = ei + E;
  const int NBK = (N + NPB - 1) / NPB;  // 98
  const int ncnt = NBK * 16;

  char* ws = (char*)d_ws;
  size_t o = 0;
  auto take = [&](size_t b) -> char* {
    char* p = ws + o;
    o += (b + 255) & ~(size_t)255;
    return p;
  };
  bf16*  hb0  = (bf16*)take((size_t)N * 128 * 2);
  bf16*  hb1  = (bf16*)take((size_t)N * 128 * 2);
  bf16*  Bp1  = (bf16*)take((size_t)D_IN * 128 * 2);
  bf16*  Bp2  = (bf16*)take((size_t)D_HID * 128 * 2);
  bf16*  Bp3  = (bf16*)take((size_t)D_HID * 128 * 2);
  float* fcwT = (float*)take((size_t)2048 * 4);
  int*   rptr = (int*)take((size_t)(N + 1) * 4);
  int*   gcnt = (int*)take((size_t)ncnt * 4);
  int2*  bins = (int2*)take((size_t)NBK * BCAP * 8);
  int*   esw  = (int*)take((size_t)E * 4);
  (void)ws_size; (void)n_in; (void)out_size;

  k_prep<<<256, 256, 0, stream>>>(W1, W2, W3, fcw, Bp1, Bp2, Bp3, fcwT, gcnt, ncnt);

  int bb = (E + 2047) / 2048;           // 306 bin blocks
  int gb = (N + 63) / 64;               // 782 gemm blocks
  k_bin_gemm1<<<bb + gb, 256, 0, stream>>>(srcI, dstI, ew, E, gcnt, bins, bb,
                                           x, Bp1, hb0, N);
  k_build<<<NBK, 512, 0, stream>>>(bins, gcnt, rptr, esw, N, NBK);

  float* emb = (float*)d_out;
  float* lsm = emb + (size_t)N * 128;
  int ab = (N + 7) / 8;

  k_agg<<<ab, 256, 0, stream>>>(hb0, rptr, esw, b1, hb1, N);
  k_gemm5<D_HID><<<gb, 256, 0, stream>>>(hb1, Bp2, hb0, N);
  k_agg<<<ab, 256, 0, stream>>>(hb0, rptr, esw, b2, hb1, N);
  k_gemm5<D_HID><<<gb, 256, 0, stream>>>(hb1, Bp3, hb0, N);
  k_agg_f32<<<ab, 256, 0, stream>>>(hb0, rptr, esw, b3, emb, N);
  k_fc_lsm<<<(N + 255) / 256, 256, 0, stream>>>(emb, fcwT, fcb, lsm, N);
}

// Round 18
// 160.687 us; speedup vs baseline: 1.0336x; 1.0137x over previous
//
#include <hip/hip_runtime.h>

#define D_IN 256
#define D_HID 128
#define NPB 256          // nodes per bucket
#define BCAP 4096        // per-bucket capacity (mean ~3189, +16 sigma)

typedef __bf16 bf16;
typedef bf16 bf16x8 __attribute__((ext_vector_type(8)));
typedef float f32x4 __attribute__((ext_vector_type(4)));
typedef unsigned short u16;
typedef const __attribute__((address_space(1))) unsigned gu32;
typedef __attribute__((address_space(3))) unsigned lu32;

__device__ __forceinline__ float bfw(int e) {
  union { u16 u; bf16 b; } cv;
  cv.u = (u16)(((unsigned)e) >> 16);
  return (float)cv.b;
}

// ---------------- prep: zero padded bucket counters + pack W + fcwT ----------
__global__ void k_prep(const float* __restrict__ W1, const float* __restrict__ W2,
                       const float* __restrict__ W3, const float* __restrict__ fcw,
                       bf16* __restrict__ B1, bf16* __restrict__ B2,
                       bf16* __restrict__ B3, float* __restrict__ fcwT,
                       int* __restrict__ gcnt, int ncnt) {
  int idx = blockIdx.x * blockDim.x + threadIdx.x;
  {
    const float* W; bf16* B; int r;
    if (idx < 32768)      { W = W1; B = B1; r = idx; }
    else if (idx < 49152) { W = W2; B = B2; r = idx - 32768; }
    else                  { W = W3; B = B3; r = idx - 49152; }
    int e = r & 7, l = (r >> 3) & 63, f = r >> 9;
    int ct = f & 7, kt = f >> 3;
    int k = kt * 32 + ((l >> 4) << 3) + e;
    int c = ct * 16 + (l & 15);
    B[r] = (bf16)W[k * 128 + c];
  }
  if (idx < 2048) {
    int c = idx >> 7, k = idx & 127;
    fcwT[idx] = fcw[k * 16 + c];
  }
  if (idx < ncnt) gcnt[idx] = 0;
}

// ---------------- merged: CSR bin (blocks < BB)  ||  gemm1 x@W1 (rest) -------
// 32 KB LDS; bin uses 256 buckets (d>>8), entry = src:16 | dlocal:8 | bucket:8.
__global__ __launch_bounds__(256) void k_bin_gemm1(
    const int* __restrict__ src, const int* __restrict__ dst,
    const float* __restrict__ ew, int E, int* __restrict__ gcnt,
    int2* __restrict__ bins, int BB,
    const float* __restrict__ x, const bf16* __restrict__ Bp,
    bf16* __restrict__ Hb, int N) {
  __shared__ __align__(16) char smraw[32768];
  const int t = threadIdx.x;

  if (blockIdx.x < BB) {
    int* lcnt  = (int*)smraw;           // 256
    int* lbase = lcnt + 256;
    int* lcur  = lcnt + 512;
    int* gbase = lcnt + 768;
    int* stotp = lcnt + 1024;
    int2* stage = (int2*)(smraw + 8192); // 16 KB
    const int e0 = blockIdx.x * 2048;

    lcnt[t] = 0;
    __syncthreads();

    int2 ent[8]; int bk[8];
    #pragma unroll
    for (int i = 0; i < 8; ++i) {
      int e = e0 + i * 256 + t;
      bool v = e < E;
      int d = v ? dst[e] : 0;
      int s = v ? src[e] : 0;
      float w = v ? ew[e] : 0.f;
      int b = d >> 8;
      bk[i] = v ? b : -1;
      ent[i] = make_int2(s | ((d & 255) << 16) | (b << 24), __float_as_int(w));
      if (v) atomicAdd(&lcnt[b], 1);
    }
    __syncthreads();

    int v = lcnt[t];
    lbase[t] = v;
    __syncthreads();
    for (int off = 1; off < 256; off <<= 1) {
      int u = (t >= off) ? lbase[t - off] : 0;
      __syncthreads();
      lbase[t] += u;
      __syncthreads();
    }
    if (t == 255) *stotp = lbase[255];
    {
      int ex = lbase[t] - v;
      lbase[t] = ex;
      lcur[t] = ex;
      gbase[t] = (v > 0) ? atomicAdd(&gcnt[t * 16], v) : 0;
    }
    __syncthreads();

    #pragma unroll
    for (int i = 0; i < 8; ++i) {
      if (bk[i] >= 0) {
        int pos = atomicAdd(&lcur[bk[i]], 1);
        stage[pos] = ent[i];
      }
    }
    __syncthreads();

    const int tot = *stotp;
    for (int j = t; j < tot; j += 256) {
      int2 en = stage[j];
      int b = ((unsigned)en.x >> 24) & 0xFF;
      int gp = gbase[b] + (j - lbase[b]);
      if (gp < BCAP)
        bins[(size_t)b * BCAP + gp] = make_int2(en.x & 0x00FFFFFF, en.y);
    }
  } else {
    constexpr int K = 256;
    bf16* Bs = (bf16*)smraw;            // 32 KB (one chunk = kt 0..3)
    const int wave = t >> 6;
    const int lane = t & 63;
    const int l16 = lane & 15;
    const int g = lane >> 4;
    const int row0 = (blockIdx.x - BB) * 64 + wave * 16;
    const int arow = row0 + l16;
    const int arow_c = (arow < N) ? arow : (N - 1);

    #pragma unroll
    for (int i = 0; i < 8; ++i) {
      const bf16* gsrc = Bp + (size_t)(i * 256 + t) * 8;
      bf16* ldst = Bs + (size_t)(i * 256 + (t & ~63)) * 8;
      __builtin_amdgcn_global_load_lds((gu32*)gsrc, (lu32*)ldst, 16, 0, 0);
    }

    bf16x8 afr[8];
    {
      const float* Af = x + (size_t)arow_c * K + g * 8;
      f32x4 f0[8], f1[8];
      #pragma unroll
      for (int kt = 0; kt < 8; ++kt) {
        f0[kt] = *reinterpret_cast<const f32x4*>(Af + kt * 32);
        f1[kt] = *reinterpret_cast<const f32x4*>(Af + kt * 32 + 4);
      }
      #pragma unroll
      for (int kt = 0; kt < 8; ++kt) {
        bf16x8 a;
        a[0] = (bf16)f0[kt][0]; a[1] = (bf16)f0[kt][1];
        a[2] = (bf16)f0[kt][2]; a[3] = (bf16)f0[kt][3];
        a[4] = (bf16)f1[kt][0]; a[5] = (bf16)f1[kt][1];
        a[6] = (bf16)f1[kt][2]; a[7] = (bf16)f1[kt][3];
        afr[kt] = a;
      }
    }
    __syncthreads();

    f32x4 acc[8];
    #pragma unroll
    for (int ct = 0; ct < 8; ++ct) acc[ct] = f32x4{0.f, 0.f, 0.f, 0.f};
    #pragma unroll
    for (int kt = 0; kt < 4; ++kt) {
      #pragma unroll
      for (int ct = 0; ct < 8; ++ct) {
        bf16x8 b = *reinterpret_cast<const bf16x8*>(Bs + (kt * 8 + ct) * 512 + lane * 8);
        acc[ct] = __builtin_amdgcn_mfma_f32_16x16x32_bf16(afr[kt], b, acc[ct], 0, 0, 0);
      }
    }
    __syncthreads();

    #pragma unroll
    for (int i = 0; i < 8; ++i) {
      const bf16* gsrc = Bp + (size_t)((i + 8) * 256 + t) * 8;
      bf16* ldst = Bs + (size_t)(i * 256 + (t & ~63)) * 8;
      __builtin_amdgcn_global_load_lds((gu32*)gsrc, (lu32*)ldst, 16, 0, 0);
    }
    __syncthreads();

    #pragma unroll
    for (int kt = 4; kt < 8; ++kt) {
      #pragma unroll
      for (int ct = 0; ct < 8; ++ct) {
        bf16x8 b = *reinterpret_cast<const bf16x8*>(Bs + ((kt - 4) * 8 + ct) * 512 + lane * 8);
        acc[ct] = __builtin_amdgcn_mfma_f32_16x16x32_bf16(afr[kt], b, acc[ct], 0, 0, 0);
      }
    }

    const int orow = row0 + 4 * g;
    #pragma unroll
    for (int ct = 0; ct < 8; ++ct) {
      #pragma unroll
      for (int r = 0; r < 4; ++r) {
        if (orow + r < N)
          Hb[(size_t)(orow + r) * 128 + ct * 16 + l16] = (bf16)acc[ct][r];
      }
    }
  }
}

// ---------------- per-bucket build (self-computed prefix) -> rptr, esw -------
// 196 blocks x 256 nodes. esw entry: bf16-weight bits <<16 | src.
__global__ __launch_bounds__(512) void k_build(const int2* __restrict__ bins,
                                               const int* __restrict__ gcnt,
                                               int* __restrict__ rptr,
                                               int* __restrict__ esw, int N, int NBK) {
  __shared__ int deg[256], sm[256], cur[256];
  __shared__ int pre[256];
  const int b = blockIdx.x, t = threadIdx.x;
  const int n0 = b << 8;
  if (t < 256) {
    deg[t] = 0;
    pre[t] = (t < NBK) ? min(gcnt[t * 16], BCAP) : 0;
  }
  __syncthreads();
  for (int off = 1; off < 256; off <<= 1) {
    int u = (t < 256 && t >= off) ? pre[t - off] : 0;
    __syncthreads();
    if (t < 256) pre[t] += u;
    __syncthreads();
  }
  const int cnt = min(gcnt[b * 16], BCAP);
  const int base = pre[b] - cnt;
  if (b == 0 && t == 0) rptr[N] = pre[NBK - 1];
  const int2* bp = bins + (size_t)b * BCAP;
  for (int i = t; i < cnt; i += 512) atomicAdd(&deg[(bp[i].x >> 16) & 255], 1);
  __syncthreads();
  if (t < 256) sm[t] = deg[t];
  __syncthreads();
  for (int off = 1; off < 256; off <<= 1) {
    int u = (t < 256 && t >= off) ? sm[t - off] : 0;
    __syncthreads();
    if (t < 256) sm[t] += u;
    __syncthreads();
  }
  if (t < 256) {
    int ex = sm[t] - deg[t];
    cur[t] = ex;
    if (n0 + t < N) rptr[n0 + t] = base + ex;
  }
  __syncthreads();
  for (int i = t; i < cnt; i += 512) {
    int2 en = bp[i];
    int pos = atomicAdd(&cur[(en.x >> 16) & 255], 1);
    union { bf16 b; u16 u; } cv;
    cv.b = (bf16)__int_as_float(en.y);
    esw[base + pos] = (((int)cv.u) << 16) | (en.x & 0xFFFF);
  }
}

// ---------------- MFMA GEMM (layers 2/3): bf16 A, async B stage --------------
template<int K>
__global__ __launch_bounds__(256) void k_gemm5(const bf16* __restrict__ Ain,
                                               const bf16* __restrict__ Bp,
                                               bf16* __restrict__ Hb, int N) {
  constexpr int NKT = K / 32;
  constexpr int NST = (K * 128) / (256 * 8);
  __shared__ bf16 Bs[K * 128];
  const int t = threadIdx.x;
  const int wave = t >> 6;
  const int lane = t & 63;
  const int l16 = lane & 15;
  const int g = lane >> 4;
  const int row0 = blockIdx.x * 64 + wave * 16;
  const int arow = row0 + l16;
  const int arow_c = (arow < N) ? arow : (N - 1);

  #pragma unroll
  for (int i = 0; i < NST; ++i) {
    const bf16* gsrc = Bp + (size_t)(i * 256 + t) * 8;
    bf16* ldst = Bs + (size_t)(i * 256 + (t & ~63)) * 8;
    __builtin_amdgcn_global_load_lds((gu32*)gsrc, (lu32*)ldst, 16, 0, 0);
  }

  bf16x8 afr[NKT];
  const bf16* Ab = Ain + (size_t)arow_c * K + g * 8;
  #pragma unroll
  for (int kt = 0; kt < NKT; ++kt)
    afr[kt] = *reinterpret_cast<const bf16x8*>(Ab + kt * 32);

  __syncthreads();

  f32x4 acc[8];
  #pragma unroll
  for (int ct = 0; ct < 8; ++ct) acc[ct] = f32x4{0.f, 0.f, 0.f, 0.f};
  #pragma unroll
  for (int kt = 0; kt < NKT; ++kt) {
    #pragma unroll
    for (int ct = 0; ct < 8; ++ct) {
      bf16x8 b = *reinterpret_cast<const bf16x8*>(Bs + (kt * 8 + ct) * 512 + lane * 8);
      acc[ct] = __builtin_amdgcn_mfma_f32_16x16x32_bf16(afr[kt], b, acc[ct], 0, 0, 0);
    }
  }

  const int orow = row0 + 4 * g;
  #pragma unroll
  for (int ct = 0; ct < 8; ++ct) {
    #pragma unroll
    for (int r = 0; r < 4; ++r) {
      if (orow + r < N)
        Hb[(size_t)(orow + r) * 128 + ct * 16 + l16] = (bf16)acc[ct][r];
    }
  }
}

// ---------------- aggregation (layers 1/2): bf16 out + relu ------------------
__global__ __launch_bounds__(256) void k_agg(const bf16* __restrict__ H,
                                             const int* __restrict__ rptr,
                                             const int* __restrict__ esw,
                                             const float* __restrict__ bias,
                                             bf16* __restrict__ out, int N) {
  const int wv = threadIdx.x >> 6;
  const int lane = threadIdx.x & 63;
  const int node = blockIdx.x * 8 + wv * 2 + (lane >> 5);
  if (node >= N) return;
  const int l16 = lane & 15;
  const int slot = (lane >> 4) & 1;
  const int p1 = rptr[node + 1];
  float a[8];
  #pragma unroll
  for (int j = 0; j < 8; ++j) a[j] = 0.f;

  int p = rptr[node] + slot;
  for (; p + 2 < p1; p += 4) {
    int e0 = esw[p];
    int e1 = esw[p + 2];
    bf16x8 h0 = *reinterpret_cast<const bf16x8*>(H + (size_t)(e0 & 0xFFFF) * 128 + l16 * 8);
    bf16x8 h1 = *reinterpret_cast<const bf16x8*>(H + (size_t)(e1 & 0xFFFF) * 128 + l16 * 8);
    float w0 = bfw(e0), w1 = bfw(e1);
    #pragma unroll
    for (int j = 0; j < 8; ++j)
      a[j] += w0 * (float)h0[j] + w1 * (float)h1[j];
  }
  if (p < p1) {
    int e0 = esw[p];
    bf16x8 h0 = *reinterpret_cast<const bf16x8*>(H + (size_t)(e0 & 0xFFFF) * 128 + l16 * 8);
    float w0 = bfw(e0);
    #pragma unroll
    for (int j = 0; j < 8; ++j)
      a[j] += w0 * (float)h0[j];
  }
  #pragma unroll
  for (int j = 0; j < 8; ++j) a[j] += __shfl_xor(a[j], 16);

  if ((lane & 16) == 0) {
    float4 b0 = *reinterpret_cast<const float4*>(bias + l16 * 8);
    float4 b1 = *reinterpret_cast<const float4*>(bias + l16 * 8 + 4);
    bf16x8 o;
    o[0] = (bf16)fmaxf(a[0] + b0.x, 0.f); o[1] = (bf16)fmaxf(a[1] + b0.y, 0.f);
    o[2] = (bf16)fmaxf(a[2] + b0.z, 0.f); o[3] = (bf16)fmaxf(a[3] + b0.w, 0.f);
    o[4] = (bf16)fmaxf(a[4] + b1.x, 0.f); o[5] = (bf16)fmaxf(a[5] + b1.y, 0.f);
    o[6] = (bf16)fmaxf(a[6] + b1.z, 0.f); o[7] = (bf16)fmaxf(a[7] + b1.w, 0.f);
    *reinterpret_cast<bf16x8*>(out + (size_t)node * 128 + l16 * 8) = o;
  }
}

// ---------------- aggregation (final layer): emb = agg(G) + b (f32) ----------
__global__ __launch_bounds__(256) void k_agg_f32(const bf16* __restrict__ H,
                                                 const int* __restrict__ rptr,
                                                 const int* __restrict__ esw,
                                                 const float* __restrict__ bias,
                                                 float* __restrict__ out, int N) {
  const int wv = threadIdx.x >> 6;
  const int lane = threadIdx.x & 63;
  const int node = blockIdx.x * 8 + wv * 2 + (lane >> 5);
  if (node >= N) return;
  const int l16 = lane & 15;
  const int slot = (lane >> 4) & 1;
  const int p1 = rptr[node + 1];
  float a[8];
  #pragma unroll
  for (int j = 0; j < 8; ++j) a[j] = 0.f;

  int p = rptr[node] + slot;
  for (; p + 2 < p1; p += 4) {
    int e0 = esw[p];
    int e1 = esw[p + 2];
    bf16x8 h0 = *reinterpret_cast<const bf16x8*>(H + (size_t)(e0 & 0xFFFF) * 128 + l16 * 8);
    bf16x8 h1 = *reinterpret_cast<const bf16x8*>(H + (size_t)(e1 & 0xFFFF) * 128 + l16 * 8);
    float w0 = bfw(e0), w1 = bfw(e1);
    #pragma unroll
    for (int j = 0; j < 8; ++j)
      a[j] += w0 * (float)h0[j] + w1 * (float)h1[j];
  }
  if (p < p1) {
    int e0 = esw[p];
    bf16x8 h0 = *reinterpret_cast<const bf16x8*>(H + (size_t)(e0 & 0xFFFF) * 128 + l16 * 8);
    float w0 = bfw(e0);
    #pragma unroll
    for (int j = 0; j < 8; ++j)
      a[j] += w0 * (float)h0[j];
  }
  #pragma unroll
  for (int j = 0; j < 8; ++j) a[j] += __shfl_xor(a[j], 16);

  if ((lane & 16) == 0) {
    float4 b0 = *reinterpret_cast<const float4*>(bias + l16 * 8);
    float4 b1 = *reinterpret_cast<const float4*>(bias + l16 * 8 + 4);
    f32x4 o0 = {a[0] + b0.x, a[1] + b0.y, a[2] + b0.z, a[3] + b0.w};
    f32x4 o1 = {a[4] + b1.x, a[5] + b1.y, a[6] + b1.z, a[7] + b1.w};
    float* op = out + (size_t)node * 128 + l16 * 8;
    *reinterpret_cast<f32x4*>(op) = o0;
    *reinterpret_cast<f32x4*>(op + 4) = o1;
  }
}

// ---------------- fc + log_softmax: one node per thread, fcw staged in LDS ----
__global__ __launch_bounds__(256) void k_fc_lsm(const float* __restrict__ emb,
                                                const float* __restrict__ fcwT,
                                                const float* __restrict__ fcb,
                                                float* __restrict__ out, int N) {
  __shared__ float wl[16 * 128];
  __shared__ float fb[16];
  const int t = threadIdx.x;
  {
    const float4* s4 = reinterpret_cast<const float4*>(fcwT);
    float4* d4 = reinterpret_cast<float4*>(wl);
    d4[t] = s4[t];
    d4[t + 256] = s4[t + 256];
  }
  if (t < 16) fb[t] = fcb[t];
  __syncthreads();

  const int node = blockIdx.x * 256 + t;
  if (node >= N) return;
  const float4* er = reinterpret_cast<const float4*>(emb + (size_t)node * 128);

  float acc[16];
  #pragma unroll
  for (int c = 0; c < 16; ++c) acc[c] = fb[c];

  #pragma unroll 4
  for (int k4 = 0; k4 < 32; ++k4) {
    float4 e = er[k4];
    #pragma unroll
    for (int c = 0; c < 16; ++c) {
      float4 w = reinterpret_cast<const float4*>(wl + c * 128)[k4];
      acc[c] += e.x * w.x + e.y * w.y + e.z * w.z + e.w * w.w;
    }
  }

  float m = acc[0];
  #pragma unroll
  for (int c = 1; c < 16; ++c) m = fmaxf(m, acc[c]);
  float s = 0.f;
  #pragma unroll
  for (int c = 0; c < 16; ++c) s += __expf(acc[c] - m);
  float lse = m + __logf(s);
  float* op = out + (size_t)node * 16;
  #pragma unroll
  for (int c4 = 0; c4 < 4; ++c4) {
    f32x4 o = {acc[c4 * 4] - lse, acc[c4 * 4 + 1] - lse,
               acc[c4 * 4 + 2] - lse, acc[c4 * 4 + 3] - lse};
    *reinterpret_cast<f32x4*>(op + c4 * 4) = o;
  }
}

extern "C" void kernel_launch(void* const* d_in, const int* in_sizes, int n_in,
                              void* d_out, int out_size, void* d_ws, size_t ws_size,
                              hipStream_t stream) {
  const float* x   = (const float*)d_in[0];
  const float* ew  = (const float*)d_in[1];
  const float* W1  = (const float*)d_in[2];
  const float* b1  = (const float*)d_in[3];
  const float* W2  = (const float*)d_in[4];
  const float* b2  = (const float*)d_in[5];
  const float* W3  = (const float*)d_in[6];
  const float* b3  = (const float*)d_in[7];
  const float* fcw = (const float*)d_in[8];
  const float* fcb = (const float*)d_in[9];
  const int*   ei  = (const int*)d_in[10];

  const int N = in_sizes[0] / D_IN;     // 50000
  const int E = in_sizes[1];            // 625000
  const int* srcI = ei;
  const int* dstI = ei + E;
  const int NBK = (N + NPB - 1) / NPB;  // 196
  const int ncnt = NBK * 16;

  char* ws = (char*)d_ws;
  size_t o = 0;
  auto take = [&](size_t b) -> char* {
    char* p = ws + o;
    o += (b + 255) & ~(size_t)255;
    return p;
  };
  bf16*  hb0  = (bf16*)take((size_t)N * 128 * 2);
  bf16*  hb1  = (bf16*)take((size_t)N * 128 * 2);
  bf16*  Bp1  = (bf16*)take((size_t)D_IN * 128 * 2);
  bf16*  Bp2  = (bf16*)take((size_t)D_HID * 128 * 2);
  bf16*  Bp3  = (bf16*)take((size_t)D_HID * 128 * 2);
  float* fcwT = (float*)take((size_t)2048 * 4);
  int*   rptr = (int*)take((size_t)(N + 1) * 4);
  int*   gcnt = (int*)take((size_t)ncnt * 4);
  int2*  bins = (int2*)take((size_t)NBK * BCAP * 8);
  int*   esw  = (int*)take((size_t)E * 4);
  (void)ws_size; (void)n_in; (void)out_size;

  k_prep<<<256, 256, 0, stream>>>(W1, W2, W3, fcw, Bp1, Bp2, Bp3, fcwT, gcnt, ncnt);

  int bb = (E + 2047) / 2048;           // 306 bin blocks
  int gb = (N + 63) / 64;               // 782 gemm blocks
  k_bin_gemm1<<<bb + gb, 256, 0, stream>>>(srcI, dstI, ew, E, gcnt, bins, bb,
                                           x, Bp1, hb0, N);
  k_build<<<NBK, 512, 0, stream>>>(bins, gcnt, rptr, esw, N, NBK);

  float* emb = (float*)d_out;
  float* lsm = emb + (size_t)N * 128;
  int ab = (N + 7) / 8;

  k_agg<<<ab, 256, 0, stream>>>(hb0, rptr, esw, b1, hb1, N);
  k_gemm5<D_HID><<<gb, 256, 0, stream>>>(hb1, Bp2, hb0, N);
  k_agg<<<ab, 256, 0, stream>>>(hb0, rptr, esw, b2, hb1, N);
  k_gemm5<D_HID><<<gb, 256, 0, stream>>>(hb1, Bp3, hb0, N);
  k_agg_f32<<<ab, 256, 0, stream>>>(hb0, rptr, esw, b3, emb, N);
  k_fc_lsm<<<(N + 255) / 256, 256, 0, stream>>>(emb, fcwT, fcb, lsm, N);
}